// Round 5
// baseline (3036.198 us; speedup 1.0000x reference)
//
#include <hip/hip_runtime.h>
#include <stdint.h>

#define T_STEPS 512
#define BATCH   128
#define HID     512
#define KTOT    1024

typedef __attribute__((ext_vector_type(8))) short          bf16x8;
typedef __attribute__((ext_vector_type(8))) unsigned short u16x8;
typedef __attribute__((ext_vector_type(4))) float          f32x4;

__device__ inline unsigned short f2bf(float f) {
    union { float f; unsigned u; } x; x.f = f;
    unsigned r = x.u + 0x7FFFu + ((x.u >> 16) & 1u);   // RNE
    return (unsigned short)(r >> 16);
}

__device__ inline float sigmoidf_(float x) { return 1.f / (1.f + __expf(-x)); }
__device__ inline float tanhf_(float x)    { float e = __expf(2.f * x); return 1.f - 2.f / (e + 1.f); }

// one-shot fp32 -> bf16 cast of the input sequence
__global__ void cast_x_kernel(const float* __restrict__ x, unsigned short* __restrict__ y, int n) {
    int i = (blockIdx.x * blockDim.x + threadIdx.x) * 8;
    if (i >= n) return;
    float4 a = *(const float4*)(x + i);
    float4 b = *(const float4*)(x + i + 4);
    u16x8 v;
    v[0] = f2bf(a.x); v[1] = f2bf(a.y); v[2] = f2bf(a.z); v[3] = f2bf(a.w);
    v[4] = f2bf(b.x); v[5] = f2bf(b.y); v[6] = f2bf(b.z); v[7] = f2bf(b.w);
    *(u16x8*)(y + i) = v;
}

// load 32B of x row-slice as packed bf16 (converting if source is fp32)
__device__ inline void load_x32(const float* xf, const unsigned short* xbf, int use_xbf,
                                size_t off, uint4& a, uint4& b) {
    if (use_xbf) {
        const uint4* p = (const uint4*)(xbf + off);
        a = p[0]; b = p[1];
    } else {
        const float4* p = (const float4*)(xf + off);
        float4 f0 = p[0], f1 = p[1], f2 = p[2], f3 = p[3];
        u16x8 v;
        v[0] = f2bf(f0.x); v[1] = f2bf(f0.y); v[2] = f2bf(f0.z); v[3] = f2bf(f0.w);
        v[4] = f2bf(f1.x); v[5] = f2bf(f1.y); v[6] = f2bf(f1.z); v[7] = f2bf(f1.w);
        a = *(uint4*)&v;
        u16x8 w;
        w[0] = f2bf(f2.x); w[1] = f2bf(f2.y); w[2] = f2bf(f2.z); w[3] = f2bf(f2.w);
        w[4] = f2bf(f3.x); w[5] = f2bf(f3.y); w[6] = f2bf(f3.z); w[7] = f2bf(f3.w);
        b = *(uint4*)&w;
    }
}

// Persistent LSTM. grid = 128 WGs (8 batch-groups x 16 col-groups), block = 512.
// Exchange readiness via ONE counter per (step, batch-group): each wave
// atomicAdds +1 after draining its own h publish stores (8 waves x 16 WGs ->
// target 128). Consumers poll with a single lane per wave. This removes the
// baseline's third barrier and cuts poll traffic on the hot line by 16x.
// 2 barriers/step.
__global__ __launch_bounds__(512, 2) void lstm_kernel(
    const float* __restrict__ xf,
    const unsigned short* __restrict__ xbf,
    const float* __restrict__ Wf, const float* __restrict__ bfv,
    const float* __restrict__ Wi, const float* __restrict__ biv,
    const float* __restrict__ Wg, const float* __restrict__ bgv,
    const float* __restrict__ Wo, const float* __restrict__ bov,
    float* __restrict__ out,
    unsigned int* __restrict__ ctr,        // [T][8] counters, stride 16 dwords
    unsigned short* __restrict__ hbuf,     // [2][128][512] bf16, bypass-access only
    int use_xbf)
{
    // comb rows padded to 1048 shorts; x in cols 0..511, h in 512..1023.
    __shared__ __align__(16) unsigned short comb[16][1048];
    __shared__ float gatesl[4][16][33];

    const int tid  = threadIdx.x;
    const int bgc  = blockIdx.x >> 4;    // batch group 0..7
    const int cg   = blockIdx.x & 15;    // col group 0..15
    const int w    = tid >> 6;
    const int lane = tid & 63;
    const int gate = w & 3;              // 0=f 1=i 2=g 3=o
    const int uh   = w >> 2;
    const int n    = lane & 15;
    const int quad = lane >> 4;
    const int unit = cg * 32 + uh * 16 + n;

    const float* Wp = (gate == 0) ? Wf : (gate == 1) ? Wi : (gate == 2) ? Wg : Wo;
    const float* bp = (gate == 0) ? bfv : (gate == 1) ? biv : (gate == 2) ? bgv : bov;
    const float bias = bp[unit];

    // ---- preload W slice into registers as bf16 B-fragments (once) ----
    bf16x8 wfr[32];
    const float* wrow = Wp + (size_t)unit * KTOT;
#pragma unroll
    for (int kk = 0; kk < 32; ++kk) {
        const float4* p = (const float4*)(wrow + kk * 32 + quad * 8);
        float4 a = p[0], b = p[1];
        u16x8 v;
        v[0] = f2bf(a.x); v[1] = f2bf(a.y); v[2] = f2bf(a.z); v[3] = f2bf(a.w);
        v[4] = f2bf(b.x); v[5] = f2bf(b.y); v[6] = f2bf(b.z); v[7] = f2bf(b.w);
        wfr[kk] = (bf16x8)v;
    }

    const int srow = tid >> 5;   // staging row 0..15 (wave w owns rows 2w, 2w+1)
    const int scol = tid & 31;   // 16 shorts (32B) per thread per row

    // cell-thread mapping: this thread owns (bc, uc) forever; c lives in a register
    const int bc = srow, uc = scol;
    float creg = 0.f;
    const int bglob = bgc * 16 + bc;
    const int uglob = cg * 32 + uc;
    const int bgrow = bgc * 16 + srow;   // == bglob

    const size_t xstride = (size_t)HID;

    // ---- prologue: stage x_0, zero h region ----
    {
        uint4 a, b;
        load_x32(xf, xbf, use_xbf, ((size_t)(0 * BATCH + bgrow)) * xstride + scol * 16, a, b);
        *(uint4*)&comb[srow][scol * 16]     = a;
        *(uint4*)&comb[srow][scol * 16 + 8] = b;
        uint4 z = {0u, 0u, 0u, 0u};
        *(uint4*)&comb[srow][512 + scol * 16]     = z;
        *(uint4*)&comb[srow][512 + scol * 16 + 8] = z;
    }
    __syncthreads();

    // ---- x-MFMA for t=0 ----
    f32x4 axa = {0.f, 0.f, 0.f, 0.f}, axb = {0.f, 0.f, 0.f, 0.f};
#pragma unroll
    for (int kk = 0; kk < 16; kk += 2) {
        bf16x8 a0 = *(const bf16x8*)&comb[n][kk * 32 + quad * 8];
        bf16x8 a1 = *(const bf16x8*)&comb[n][(kk + 1) * 32 + quad * 8];
        axa = __builtin_amdgcn_mfma_f32_16x16x32_bf16(a0, wfr[kk],     axa, 0, 0, 0);
        axb = __builtin_amdgcn_mfma_f32_16x16x32_bf16(a1, wfr[kk + 1], axb, 0, 0, 0);
    }

    // ---- prefetch x_1 into registers ----
    uint4 pfa, pfb;
    load_x32(xf, xbf, use_xbf, ((size_t)(1 * BATCH + bgrow)) * xstride + scol * 16, pfa, pfb);

    for (int t = 0; t < T_STEPS; ++t) {
        // ---- phase A: one-lane-per-wave counter poll, then h load + LDS stage ----
        if (t > 0) {
            if (lane == 0) {
                const unsigned int* cp = ctr + ((size_t)(t - 1) * 8 + bgc) * 16;
                while (__hip_atomic_load(cp, __ATOMIC_RELAXED, __HIP_MEMORY_SCOPE_AGENT) < 128u) {}
            }
            // wave proceeds only when lane 0 exits the spin
            const unsigned long long* src = (const unsigned long long*)
                (hbuf + (size_t)((t - 1) & 1) * BATCH * HID + (size_t)bgrow * HID + scol * 16);
            unsigned long long v0 = __hip_atomic_load(src + 0, __ATOMIC_RELAXED, __HIP_MEMORY_SCOPE_AGENT);
            unsigned long long v1 = __hip_atomic_load(src + 1, __ATOMIC_RELAXED, __HIP_MEMORY_SCOPE_AGENT);
            unsigned long long v2 = __hip_atomic_load(src + 2, __ATOMIC_RELAXED, __HIP_MEMORY_SCOPE_AGENT);
            unsigned long long v3 = __hip_atomic_load(src + 3, __ATOMIC_RELAXED, __HIP_MEMORY_SCOPE_AGENT);
            uint4 a, b;
            a.x = (unsigned)v0; a.y = (unsigned)(v0 >> 32);
            a.z = (unsigned)v1; a.w = (unsigned)(v1 >> 32);
            b.x = (unsigned)v2; b.y = (unsigned)(v2 >> 32);
            b.z = (unsigned)v3; b.w = (unsigned)(v3 >> 32);
            *(uint4*)&comb[srow][512 + scol * 16]     = a;
            *(uint4*)&comb[srow][512 + scol * 16 + 8] = b;
        }
        __syncthreads();   // barrier 1: h_{t-1} staged (t=0: zeros from prologue)

        // ---- phase B: h-MFMA accumulates onto the x-partials from last iteration ----
#pragma unroll
        for (int kk = 16; kk < 32; kk += 2) {
            bf16x8 a0 = *(const bf16x8*)&comb[n][kk * 32 + quad * 8];
            bf16x8 a1 = *(const bf16x8*)&comb[n][(kk + 1) * 32 + quad * 8];
            axa = __builtin_amdgcn_mfma_f32_16x16x32_bf16(a0, wfr[kk],     axa, 0, 0, 0);
            axb = __builtin_amdgcn_mfma_f32_16x16x32_bf16(a1, wfr[kk + 1], axb, 0, 0, 0);
        }

        // ---- activations -> LDS gate exchange; also stage x_{t+1} from regs ----
#pragma unroll
        for (int r = 0; r < 4; ++r) {
            float v = axa[r] + axb[r] + bias;
            v = (gate == 2) ? tanhf_(v) : sigmoidf_(v);
            gatesl[gate][quad * 4 + r][uh * 16 + n] = v;
        }
        if (t + 1 < T_STEPS) {
            *(uint4*)&comb[srow][scol * 16]     = pfa;
            *(uint4*)&comb[srow][scol * 16 + 8] = pfb;
        }
        __syncthreads();   // barrier 2: gates + x_{t+1} staged

        // ---- phase C: cell update; publish h_t; per-wave drain + counter add ----
        float hv, cn;
        {
            float fv = gatesl[0][bc][uc], iv = gatesl[1][bc][uc];
            float gv = gatesl[2][bc][uc], ov = gatesl[3][bc][uc];
            cn = fv * creg + iv * gv;
            creg = cn;
            hv = ov * tanhf_(cn);
            // packed-pair bypass publish (issue first so the drain starts early)
            unsigned int us  = (unsigned int)f2bf(hv);
            unsigned int us1 = (unsigned int)__shfl_down((int)us, 1);
            if (t + 1 < T_STEPS && (uc & 1) == 0) {
                unsigned int pv = us | (us1 << 16);
                unsigned int* hp = (unsigned int*)(hbuf + (size_t)(t & 1) * BATCH * HID
                                                   + (size_t)bglob * HID + uglob);
                __hip_atomic_store(hp, pv, __ATOMIC_RELAXED, __HIP_MEMORY_SCOPE_AGENT);
            }
        }

        // ---- x-MFMA for t+1 (overlaps the h-store drain) ----
        if (t + 1 < T_STEPS) {
            axa = (f32x4){0.f, 0.f, 0.f, 0.f};
            axb = (f32x4){0.f, 0.f, 0.f, 0.f};
#pragma unroll
            for (int kk = 0; kk < 16; kk += 2) {
                bf16x8 a0 = *(const bf16x8*)&comb[n][kk * 32 + quad * 8];
                bf16x8 a1 = *(const bf16x8*)&comb[n][(kk + 1) * 32 + quad * 8];
                axa = __builtin_amdgcn_mfma_f32_16x16x32_bf16(a0, wfr[kk],     axa, 0, 0, 0);
                axb = __builtin_amdgcn_mfma_f32_16x16x32_bf16(a1, wfr[kk + 1], axb, 0, 0, 0);
            }
        }

        // ---- per-wave drain of h stores, then one atomicAdd per wave ----
        __builtin_amdgcn_s_waitcnt(0);
        if (lane == 0 && t + 1 < T_STEPS) {
            __hip_atomic_fetch_add(ctr + ((size_t)t * 8 + bgc) * 16, 1u,
                                   __ATOMIC_RELAXED, __HIP_MEMORY_SCOPE_AGENT);
        }

        // ---- out stores (after the exchange-critical drain) + x_{t+2} prefetch ----
        out[(size_t)t * BATCH * HID + (size_t)bglob * HID + uglob] = hv;
        if (t == T_STEPS - 1) {
            out[(size_t)T_STEPS * BATCH * HID + (size_t)bglob * HID + uglob] = hv;                 // hx
            out[(size_t)T_STEPS * BATCH * HID + BATCH * HID + (size_t)bglob * HID + uglob] = cn;   // cx
        }
        if (t + 2 < T_STEPS) {
            load_x32(xf, xbf, use_xbf,
                     ((size_t)((t + 2) * BATCH + bgrow)) * xstride + scol * 16, pfa, pfb);
        }
    }
}

extern "C" void kernel_launch(void* const* d_in, const int* in_sizes, int n_in,
                              void* d_out, int out_size, void* d_ws, size_t ws_size,
                              hipStream_t stream) {
    (void)in_sizes; (void)n_in; (void)out_size;
    const float* x   = (const float*)d_in[0];
    const float* Wf  = (const float*)d_in[1];
    const float* bfv = (const float*)d_in[2];
    const float* Wi  = (const float*)d_in[3];
    const float* biv = (const float*)d_in[4];
    const float* Wg  = (const float*)d_in[5];
    const float* bgv = (const float*)d_in[6];
    const float* Wo  = (const float*)d_in[7];
    const float* bov = (const float*)d_in[8];
    float* out = (float*)d_out;

    unsigned char* ws = (unsigned char*)d_ws;
    unsigned int*   ctr  = (unsigned int*)ws;                         // 512*8*16*4 = 256 KB
    unsigned short* hbuf = (unsigned short*)(ws + 262144);            // 2*128*512*2 = 256 KB
    unsigned short* xbf  = (unsigned short*)(ws + 524288);            // 64 MB (optional)

    size_t need = 524288 + (size_t)T_STEPS * BATCH * HID * 2;
    int use_xbf = (ws_size >= need) ? 1 : 0;

    hipMemsetAsync(ctr, 0, 262144, stream);
    if (use_xbf) {
        int nelem = T_STEPS * BATCH * HID;
        cast_x_kernel<<<nelem / (256 * 8), 256, 0, stream>>>(x, xbf, nelem);
    }
    lstm_kernel<<<dim3(128), dim3(512), 0, stream>>>(
        x, xbf, Wf, bfv, Wi, biv, Wg, bgv, Wo, bov, out, ctr, hbuf, use_xbf);
}

// Round 6
// 1899.064 us; speedup vs baseline: 1.5988x; 1.5988x over previous
//
#include <hip/hip_runtime.h>
#include <stdint.h>

#define T_STEPS 512
#define BATCH   128
#define HID     512
#define KTOT    1024

typedef __attribute__((ext_vector_type(8))) short          bf16x8;
typedef __attribute__((ext_vector_type(8))) unsigned short u16x8;
typedef __attribute__((ext_vector_type(4))) float          f32x4;

__device__ inline unsigned short f2bf(float f) {
    union { float f; unsigned u; } x; x.f = f;
    unsigned r = x.u + 0x7FFFu + ((x.u >> 16) & 1u);   // RNE
    return (unsigned short)(r >> 16);
}

__device__ inline float sigmoidf_(float x) { return 1.f / (1.f + __expf(-x)); }
__device__ inline float tanhf_(float x)    { float e = __expf(2.f * x); return 1.f - 2.f / (e + 1.f); }

// one-shot fp32 -> bf16 cast of the input sequence
__global__ void cast_x_kernel(const float* __restrict__ x, unsigned short* __restrict__ y, int n) {
    int i = (blockIdx.x * blockDim.x + threadIdx.x) * 8;
    if (i >= n) return;
    float4 a = *(const float4*)(x + i);
    float4 b = *(const float4*)(x + i + 4);
    u16x8 v;
    v[0] = f2bf(a.x); v[1] = f2bf(a.y); v[2] = f2bf(a.z); v[3] = f2bf(a.w);
    v[4] = f2bf(b.x); v[5] = f2bf(b.y); v[6] = f2bf(b.z); v[7] = f2bf(b.w);
    *(u16x8*)(y + i) = v;
}

// load 32B of x row-slice as packed bf16 (converting if source is fp32)
__device__ inline void load_x32(const float* xf, const unsigned short* xbf, int use_xbf,
                                size_t off, uint4& a, uint4& b) {
    if (use_xbf) {
        const uint4* p = (const uint4*)(xbf + off);
        a = p[0]; b = p[1];
    } else {
        const float4* p = (const float4*)(xf + off);
        float4 f0 = p[0], f1 = p[1], f2 = p[2], f3 = p[3];
        u16x8 v;
        v[0] = f2bf(f0.x); v[1] = f2bf(f0.y); v[2] = f2bf(f0.z); v[3] = f2bf(f0.w);
        v[4] = f2bf(f1.x); v[5] = f2bf(f1.y); v[6] = f2bf(f1.z); v[7] = f2bf(f1.w);
        a = *(uint4*)&v;
        u16x8 w;
        w[0] = f2bf(f2.x); w[1] = f2bf(f2.y); w[2] = f2bf(f2.z); w[3] = f2bf(f2.w);
        w[4] = f2bf(f3.x); w[5] = f2bf(f3.y); w[6] = f2bf(f3.z); w[7] = f2bf(f3.w);
        b = *(uint4*)&w;
    }
}

// Persistent LSTM. grid = 128 WGs (8 batch-groups x 16 col-groups), block = 512.
// Exchange protocol IDENTICAL to the verified 1936us baseline (16 flags/group,
// lane<16 poll, 3 barriers). NEW: wave roles are (unit-half, K-quarter), each
// wave computing ALL 4 gates from one A-fragment read (4 MFMAs per ds_read,
// ILP-4). A-fragment LDS traffic drops 4x (256KB -> 64KB per WG-step); gate
// K-partials are summed in the cell phase via gp[][] (bias+activation applied
// after the sum -- mathematically identical).
__global__ __launch_bounds__(512, 2) void lstm_kernel(
    const float* __restrict__ xf,
    const unsigned short* __restrict__ xbf,
    const float* __restrict__ Wf, const float* __restrict__ bfv,
    const float* __restrict__ Wi, const float* __restrict__ biv,
    const float* __restrict__ Wg, const float* __restrict__ bgv,
    const float* __restrict__ Wo, const float* __restrict__ bov,
    float* __restrict__ out,
    unsigned int* __restrict__ flags,      // [T][8][16] one dword per producer WG
    unsigned short* __restrict__ hbuf,     // [2][128][512] bf16, bypass-access only
    int use_xbf)
{
    // comb rows padded to 1048 shorts; x in cols 0..511, h in 512..1023.
    __shared__ __align__(16) unsigned short comb[16][1048];
    // raw gate K-partials: [K-quarter][gate][batch row][unit 0..31 (+pad to 34)]
    __shared__ float gp[4][4][16][34];

    const int tid  = threadIdx.x;
    const int bgc  = blockIdx.x >> 4;    // batch group 0..7
    const int cg   = blockIdx.x & 15;    // col group 0..15
    const int w    = tid >> 6;
    const int lane = tid & 63;
    const int kh   = w & 3;              // K-quarter 0..3
    const int uh   = w >> 2;             // unit half 0..1
    const int n    = lane & 15;
    const int quad = lane >> 4;
    const int unit = cg * 32 + uh * 16 + n;

    // ---- preload W slices: all 4 gates, this wave's K-quarter (8 chunks) ----
    bf16x8 wfr[4][8];
    {
        const float* Wptr[4] = {Wf, Wi, Wg, Wo};
#pragma unroll
        for (int g = 0; g < 4; ++g) {
            const float* wrow = Wptr[g] + (size_t)unit * KTOT;
#pragma unroll
            for (int j = 0; j < 8; ++j) {
                const int kk = (j < 4) ? (kh * 4 + j) : (16 + kh * 4 + (j - 4));
                const float4* p = (const float4*)(wrow + kk * 32 + quad * 8);
                float4 a = p[0], b = p[1];
                u16x8 v;
                v[0] = f2bf(a.x); v[1] = f2bf(a.y); v[2] = f2bf(a.z); v[3] = f2bf(a.w);
                v[4] = f2bf(b.x); v[5] = f2bf(b.y); v[6] = f2bf(b.z); v[7] = f2bf(b.w);
                wfr[g][j] = (bf16x8)v;
            }
        }
    }

    const int srow = tid >> 5;   // staging row 0..15 (wave w owns rows 2w, 2w+1)
    const int scol = tid & 31;   // 16 shorts (32B) per thread per row

    // cell-thread mapping: this thread owns (bc, uc) forever; c lives in a register
    const int bc = srow, uc = scol;
    float creg = 0.f;
    const int bglob = bgc * 16 + bc;
    const int uglob = cg * 32 + uc;
    const int bgrow = bgc * 16 + srow;   // == bglob

    // per-thread gate biases (added once, after the K-partial sum)
    float biasv[4];
    biasv[0] = bfv[uglob]; biasv[1] = biv[uglob];
    biasv[2] = bgv[uglob]; biasv[3] = bov[uglob];

    const size_t xstride = (size_t)HID;

    // ---- prologue: stage x_0, zero h region ----
    {
        uint4 a, b;
        load_x32(xf, xbf, use_xbf, ((size_t)(0 * BATCH + bgrow)) * xstride + scol * 16, a, b);
        *(uint4*)&comb[srow][scol * 16]     = a;
        *(uint4*)&comb[srow][scol * 16 + 8] = b;
        uint4 z = {0u, 0u, 0u, 0u};
        *(uint4*)&comb[srow][512 + scol * 16]     = z;
        *(uint4*)&comb[srow][512 + scol * 16 + 8] = z;
    }
    __syncthreads();

    // ---- x-MFMA for t=0 (this wave's K-quarter of the x range) ----
    f32x4 acc[4];
#pragma unroll
    for (int g = 0; g < 4; ++g) acc[g] = (f32x4){0.f, 0.f, 0.f, 0.f};
    {
        bf16x8 af[4];
#pragma unroll
        for (int j = 0; j < 4; ++j)
            af[j] = *(const bf16x8*)&comb[n][(kh * 4 + j) * 32 + quad * 8];
#pragma unroll
        for (int j = 0; j < 4; ++j)
#pragma unroll
            for (int g = 0; g < 4; ++g)
                acc[g] = __builtin_amdgcn_mfma_f32_16x16x32_bf16(af[j], wfr[g][j], acc[g], 0, 0, 0);
    }

    // ---- prefetch x_1 into registers ----
    uint4 pfa, pfb;
    load_x32(xf, xbf, use_xbf, ((size_t)(1 * BATCH + bgrow)) * xstride + scol * 16, pfa, pfb);

    for (int t = 0; t < T_STEPS; ++t) {
        // ---- per-wave poll for h_{t-1}, then wave-local load + LDS stage ----
        if (t > 0) {
            if (lane < 16) {
                unsigned int* fp = flags + ((size_t)(t - 1) * 8 + bgc) * 16 + lane;
                while (__hip_atomic_load(fp, __ATOMIC_RELAXED, __HIP_MEMORY_SCOPE_AGENT) == 0u) {}
            }
            const unsigned long long* src = (const unsigned long long*)
                (hbuf + (size_t)((t - 1) & 1) * BATCH * HID + (size_t)bgrow * HID + scol * 16);
            unsigned long long v0 = __hip_atomic_load(src + 0, __ATOMIC_RELAXED, __HIP_MEMORY_SCOPE_AGENT);
            unsigned long long v1 = __hip_atomic_load(src + 1, __ATOMIC_RELAXED, __HIP_MEMORY_SCOPE_AGENT);
            unsigned long long v2 = __hip_atomic_load(src + 2, __ATOMIC_RELAXED, __HIP_MEMORY_SCOPE_AGENT);
            unsigned long long v3 = __hip_atomic_load(src + 3, __ATOMIC_RELAXED, __HIP_MEMORY_SCOPE_AGENT);
            uint4 a, b;
            a.x = (unsigned)v0; a.y = (unsigned)(v0 >> 32);
            a.z = (unsigned)v1; a.w = (unsigned)(v1 >> 32);
            b.x = (unsigned)v2; b.y = (unsigned)(v2 >> 32);
            b.z = (unsigned)v3; b.w = (unsigned)(v3 >> 32);
            *(uint4*)&comb[srow][512 + scol * 16]     = a;
            *(uint4*)&comb[srow][512 + scol * 16 + 8] = b;
        }
        __syncthreads();   // barrier 1: h_{t-1} staged (t=0: zeros from prologue)

        // ---- h-MFMA: this wave's K-quarter of the h range, all 4 gates ----
        {
            bf16x8 af[4];
#pragma unroll
            for (int j = 0; j < 4; ++j)
                af[j] = *(const bf16x8*)&comb[n][(16 + kh * 4 + j) * 32 + quad * 8];
#pragma unroll
            for (int j = 0; j < 4; ++j)
#pragma unroll
                for (int g = 0; g < 4; ++g)
                    acc[g] = __builtin_amdgcn_mfma_f32_16x16x32_bf16(af[j], wfr[g][4 + j], acc[g], 0, 0, 0);
        }

        // ---- write raw K-partials; stage x_{t+1} from regs ----
#pragma unroll
        for (int g = 0; g < 4; ++g)
#pragma unroll
            for (int r = 0; r < 4; ++r)
                gp[kh][g][quad * 4 + r][uh * 16 + n] = acc[g][r];
        if (t + 1 < T_STEPS) {
            *(uint4*)&comb[srow][scol * 16]     = pfa;
            *(uint4*)&comb[srow][scol * 16 + 8] = pfb;
        }
        __syncthreads();   // barrier 2: partials + x_{t+1} staged

        // ---- LSTM cell: sum K-partials + bias, activate, update c; publish h ----
        {
            float s0 = gp[0][0][bc][uc] + gp[1][0][bc][uc] + gp[2][0][bc][uc] + gp[3][0][bc][uc] + biasv[0];
            float s1 = gp[0][1][bc][uc] + gp[1][1][bc][uc] + gp[2][1][bc][uc] + gp[3][1][bc][uc] + biasv[1];
            float s2 = gp[0][2][bc][uc] + gp[1][2][bc][uc] + gp[2][2][bc][uc] + gp[3][2][bc][uc] + biasv[2];
            float s3 = gp[0][3][bc][uc] + gp[1][3][bc][uc] + gp[2][3][bc][uc] + gp[3][3][bc][uc] + biasv[3];
            float fv = sigmoidf_(s0);
            float iv = sigmoidf_(s1);
            float gv = tanhf_(s2);
            float ov = sigmoidf_(s3);
            float cn = fv * creg + iv * gv;
            creg = cn;
            float hv = ov * tanhf_(cn);
            // packed-pair bypass publish (issue first so the drain starts early)
            unsigned int us  = (unsigned int)f2bf(hv);
            unsigned int us1 = (unsigned int)__shfl_down((int)us, 1);
            if ((uc & 1) == 0) {
                unsigned int pv = us | (us1 << 16);
                unsigned int* hp = (unsigned int*)(hbuf + (size_t)(t & 1) * BATCH * HID
                                                   + (size_t)bglob * HID + uglob);
                __hip_atomic_store(hp, pv, __ATOMIC_RELAXED, __HIP_MEMORY_SCOPE_AGENT);
            }
            out[(size_t)t * BATCH * HID + (size_t)bglob * HID + uglob] = hv;
            if (t == T_STEPS - 1) {
                out[(size_t)T_STEPS * BATCH * HID + (size_t)bglob * HID + uglob] = hv;                 // hx
                out[(size_t)T_STEPS * BATCH * HID + BATCH * HID + (size_t)bglob * HID + uglob] = cn;   // cx
            }
        }

        // ---- x-MFMA for t+1 (overlaps the publish drain) ----
        if (t + 1 < T_STEPS) {
#pragma unroll
            for (int g = 0; g < 4; ++g) acc[g] = (f32x4){0.f, 0.f, 0.f, 0.f};
            bf16x8 af[4];
#pragma unroll
            for (int j = 0; j < 4; ++j)
                af[j] = *(const bf16x8*)&comb[n][(kh * 4 + j) * 32 + quad * 8];
#pragma unroll
            for (int j = 0; j < 4; ++j)
#pragma unroll
                for (int g = 0; g < 4; ++g)
                    acc[g] = __builtin_amdgcn_mfma_f32_16x16x32_bf16(af[j], wfr[g][j], acc[g], 0, 0, 0);
        }

        // ---- drain bypass stores, then one flag store; prefetch x_{t+2} ----
        __builtin_amdgcn_s_waitcnt(0);
        __syncthreads();   // all waves drained
        if (tid == 0) {
            __hip_atomic_store(flags + ((size_t)t * 8 + bgc) * 16 + cg, 1u,
                               __ATOMIC_RELAXED, __HIP_MEMORY_SCOPE_AGENT);
        }
        if (t + 2 < T_STEPS) {
            load_x32(xf, xbf, use_xbf,
                     ((size_t)((t + 2) * BATCH + bgrow)) * xstride + scol * 16, pfa, pfb);
        }
    }
}

extern "C" void kernel_launch(void* const* d_in, const int* in_sizes, int n_in,
                              void* d_out, int out_size, void* d_ws, size_t ws_size,
                              hipStream_t stream) {
    (void)in_sizes; (void)n_in; (void)out_size;
    const float* x   = (const float*)d_in[0];
    const float* Wf  = (const float*)d_in[1];
    const float* bfv = (const float*)d_in[2];
    const float* Wi  = (const float*)d_in[3];
    const float* biv = (const float*)d_in[4];
    const float* Wg  = (const float*)d_in[5];
    const float* bgv = (const float*)d_in[6];
    const float* Wo  = (const float*)d_in[7];
    const float* bov = (const float*)d_in[8];
    float* out = (float*)d_out;

    unsigned char* ws = (unsigned char*)d_ws;
    unsigned int*   flags = (unsigned int*)ws;                        // 512*8*16*4 = 256 KB
    unsigned short* hbuf  = (unsigned short*)(ws + 262144);           // 2*128*512*2 = 256 KB
    unsigned short* xbf   = (unsigned short*)(ws + 524288);           // 64 MB (optional)

    size_t need = 524288 + (size_t)T_STEPS * BATCH * HID * 2;
    int use_xbf = (ws_size >= need) ? 1 : 0;

    hipMemsetAsync(flags, 0, 262144, stream);
    if (use_xbf) {
        int nelem = T_STEPS * BATCH * HID;
        cast_x_kernel<<<nelem / (256 * 8), 256, 0, stream>>>(x, xbf, nelem);
    }
    lstm_kernel<<<dim3(128), dim3(512), 0, stream>>>(
        x, xbf, Wf, bfv, Wi, biv, Wg, bgv, Wo, bov, out, flags, hbuf, use_xbf);
}